// Round 5
// baseline (485.308 us; speedup 1.0000x reference)
//
#include <hip/hip_runtime.h>
#include <math.h>

// RoutingLayer fused via split-fp16 MFMA emulation of fp32 GEMM.
// routing = x@w_gate + noise*(softplus(x@w_noise)+0.01); out = scatter(softmax(top2)).
// x: 32768x2048 fp32, w_*: 2048x64 fp32, noise: 32768x64, out: 32768x64.
//
// R8: barrier-free dataflow loop. R5-R7 (counted vmcnt, 2x occupancy,
// convert-ahead) moved routing only ~166->150us; every pipe sits at
// 12-20% because the 64 per-chunk barrier-steps re-lockstep all waves --
// pipe times SUM instead of MAX. B (1 MB, shared by all 512 blocks) is
// L2-resident: load fragments DIRECTLY global->registers (lane-linear
// 16B = perfectly coalesced 1KB/instr) instead of DMA->LDS->ds_read.
// Eliminates all LDS staging, all ds_read_b128, and ALL main-loop
// barriers/inline-asm. Manual 1-deep register double-buffer (B and x),
// 2x-unrolled loop so buffer indices are literal; compiler schedules
// waits; 16 waves/CU de-phase freely. Accumulation order unchanged =>
// bit-identical numerics.

typedef _Float16 half4v __attribute__((ext_vector_type(4)));
typedef _Float16 half8v __attribute__((ext_vector_type(8)));
typedef float f32x4 __attribute__((ext_vector_type(4)));

constexpr int DIMK = 2048;
constexpr int NEXP = 64;
constexpr int BM   = 64;         // rows per block
constexpr int NCH  = DIMK / 32;  // 64 k-chunks of 32

__device__ __forceinline__ bool gt_pair(float a, int ia, float b, int ib) {
    return (a > b) || (a == b && ia < ib);   // jax top_k: lower index wins ties
}

// ---- pre-kernel: split w' = 65536*[wg|wn] into 2 fp16 planes in B-frag order.
// ws layout: [chunk c][plane p][ntile t][lane][8 halfs]  (1KB per (c,p,t))
// B-frag (16x16x32): lane holds B[k = c*32 + (lane>>4)*8 + j][n = t*16 + (lane&15)]
__global__ __launch_bounds__(256)
void presplit_kernel(const float* __restrict__ wg, const float* __restrict__ wn,
                     _Float16* __restrict__ wsB)
{
    int gid  = blockIdx.x * 256 + threadIdx.x;   // 0..32767 = (c, t, lane)
    int lane = gid & 63;
    int t    = (gid >> 6) & 7;
    int c    = gid >> 9;
    int n    = t * 16 + (lane & 15);
    int kb   = c * 32 + ((lane >> 4) << 3);
    const float* src = (n < NEXP) ? (wg + n) : (wn + (n - NEXP));
    half8v h1, h2;
    #pragma unroll
    for (int j = 0; j < 8; ++j) {
        float w = src[(size_t)(kb + j) * NEXP] * 65536.0f;
        _Float16 a = (_Float16)w;
        h1[j] = a;
        h2[j] = (_Float16)(w - (float)a);
    }
    *(half8v*)(wsB + ((((size_t)c * 2 + 0) * 8 + t) * 64 + lane) * 8) = h1;
    *(half8v*)(wsB + ((((size_t)c * 2 + 1) * 8 + t) * 64 + lane) * 8) = h2;
}

// ---- main kernel: 512 threads = 8 waves as (mt = mtile 0..3, wnh = expert half).
// Wave tile: 16 rows x [16+16 gate cols | matching 16+16 noise cols].
__global__ __launch_bounds__(512, 4)
void routing_mfma(const float* __restrict__ x, const _Float16* __restrict__ wsB,
                  const float* __restrict__ noise, float* __restrict__ out)
{
    __shared__ float4 cand[BM][2];            // 2 KB
    __shared__ float4 res[BM];                // 1 KB

    const int tid  = threadIdx.x;
    const int lane = tid & 63;
    const int w    = tid >> 6;          // 0..7
    const int mt   = w >> 1;            // mtile (0..3): rows mt*16..mt*16+15
    const int wnh  = w & 1;             // expert half (0,1)
    const int q    = lane >> 4;
    const int cidx = lane & 15;
    const int row0 = blockIdx.x * BM;

    f32x4 acc[4] = {};                  // [tt: 0,1=gate tiles, 2,3=noise tiles]

    // A-frag source row: lane (m=cidx) of this wave's mtile, k-offset q*8
    const float* xp = x + (size_t)(row0 + mt * 16 + cidx) * DIMK + q * 8;
    // B-frag per-lane base; frag (c,p,ntile) at halfs c*8192 + p*4096 + ntile*512
    const _Float16* bbase = wsB + (size_t)lane * 8;

    half8v bA0[4], bA1[4], bB0[4], bB1[4];    // B double-buffer (literal names)
    float4 rA0, rA1, rB0, rB1;                // x double-buffer

#define LOADB(C, B0, B1)                                                     \
    {   const _Float16* p_ = bbase + (size_t)(C) * 8192;                     \
        _Pragma("unroll")                                                    \
        for (int tt = 0; tt < 4; ++tt) {                                     \
            int ntile = (tt < 2) ? (wnh * 2 + tt) : (4 + wnh * 2 + (tt - 2));\
            B0[tt] = *(const half8v*)(p_ + ntile * 512);                     \
            B1[tt] = *(const half8v*)(p_ + 4096 + ntile * 512);              \
        }                                                                    \
    }

#define LOADX(C, R0, R1)                                                     \
    {   const float* p_ = xp + (C) * 32;                                     \
        R0 = *(const float4*)(p_);                                           \
        R1 = *(const float4*)(p_ + 4);  }

#define COMPUTE(B0, B1, R0, R1)                                              \
    {   half8v af0, af1;                                                     \
        _Pragma("unroll")                                                    \
        for (int h = 0; h < 2; ++h) {                                        \
            float4 v = h ? (R1) : (R0);                                      \
            float f0 = v.x * 1024.f, f1 = v.y * 1024.f;                      \
            float f2 = v.z * 1024.f, f3 = v.w * 1024.f;                      \
            _Float16 a0 = (_Float16)f0, a1 = (_Float16)f1;                   \
            _Float16 a2 = (_Float16)f2, a3 = (_Float16)f3;                   \
            af0[h * 4 + 0] = a0; af0[h * 4 + 1] = a1;                        \
            af0[h * 4 + 2] = a2; af0[h * 4 + 3] = a3;                        \
            af1[h * 4 + 0] = (_Float16)(f0 - (float)a0);                     \
            af1[h * 4 + 1] = (_Float16)(f1 - (float)a1);                     \
            af1[h * 4 + 2] = (_Float16)(f2 - (float)a2);                     \
            af1[h * 4 + 3] = (_Float16)(f3 - (float)a3);                     \
        }                                                                    \
        _Pragma("unroll")                                                    \
        for (int tt = 0; tt < 4; ++tt) {                                     \
            acc[tt] = __builtin_amdgcn_mfma_f32_16x16x32_f16(                \
                af0, B0[tt], acc[tt], 0, 0, 0);                              \
            acc[tt] = __builtin_amdgcn_mfma_f32_16x16x32_f16(                \
                af0, B1[tt], acc[tt], 0, 0, 0);                              \
            acc[tt] = __builtin_amdgcn_mfma_f32_16x16x32_f16(                \
                af1, B0[tt], acc[tt], 0, 0, 0);                              \
        }                                                                    \
    }

    LOADB(0, bA0, bA1);
    LOADX(0, rA0, rA1);

    #pragma unroll 1
    for (int c = 0; c < NCH; c += 2) {
        // prefetch c+1 into B-set, compute c from A-set
        LOADB(c + 1, bB0, bB1);
        LOADX(c + 1, rB0, rB1);
        COMPUTE(bA0, bA1, rA0, rA1);
        // prefetch c+2 into A-set, compute c+1 from B-set
        if (c + 2 < NCH) {
            LOADB(c + 2, bA0, bA1);
            LOADX(c + 2, rA0, rA1);
        }
        COMPUTE(bB0, bB1, rB0, rB1);
    }

#undef COMPUTE
#undef LOADX
#undef LOADB

    // ---- epilogue ----
    // C/D layout: col = lane&15, row = q*4 + reg. Unscale by 2^-26 (1024*65536).
    const float s = 0x1p-26f;
    {
        float rv[2][4];
        const int rbase = row0 + mt * 16 + q * 4;
        #pragma unroll
        for (int g = 0; g < 2; ++g) {
            int e = wnh * 32 + g * 16 + cidx;
            #pragma unroll
            for (int r = 0; r < 4; ++r) {
                float nz   = noise[(size_t)(rbase + r) * NEXP + e];
                float gate = acc[g][r] * s;
                float nv   = acc[g + 2][r] * s;
                float sp   = fmaxf(nv, 0.f) + log1pf(expf(-fabsf(nv)));
                rv[g][r]   = gate + nz * (sp + 0.01f);
            }
        }
        #pragma unroll
        for (int r = 0; r < 4; ++r) {
            int e0 = wnh * 32 + cidx, e1 = e0 + 16;
            float v1, v2; int i1, i2;
            float a = rv[0][r], b = rv[1][r];
            if (a >= b) { v1 = a; i1 = e0; v2 = b; i2 = e1; }   // e0<e1: tie ok
            else        { v1 = b; i1 = e1; v2 = a; i2 = e0; }
            #pragma unroll
            for (int m = 1; m <= 8; m <<= 1) {    // butterfly across the 16-lane quad
                float b1 = __shfl_xor(v1, m); int ib1 = __shfl_xor(i1, m);
                float b2 = __shfl_xor(v2, m); int ib2 = __shfl_xor(i2, m);
                if (gt_pair(b1, ib1, v1, i1)) {
                    float o1 = v1; int oi1 = i1;
                    v1 = b1; i1 = ib1;
                    if (gt_pair(b2, ib2, o1, oi1)) { v2 = b2; i2 = ib2; }
                    else                           { v2 = o1; i2 = oi1; }
                } else if (gt_pair(b1, ib1, v2, i2)) {
                    v2 = b1; i2 = ib1;
                }
            }
            if (cidx == 0) {
                int rowb = mt * 16 + q * 4 + r;
                cand[rowb][wnh] = make_float4(v1, __int_as_float(i1),
                                              v2, __int_as_float(i2));
            }
        }
    }
    __syncthreads();

    if (tid < BM) {   // merge the two expert-half candidates, softmax
        float4 c0 = cand[tid][0], c1 = cand[tid][1];
        float mv1 = c0.x; int mi1 = __float_as_int(c0.y);
        float mv2 = c0.z; int mi2 = __float_as_int(c0.w);
        float b1 = c1.x;  int ib1 = __float_as_int(c1.y);
        float b2 = c1.z;  int ib2 = __float_as_int(c1.w);
        if (gt_pair(b1, ib1, mv1, mi1)) {
            float o1 = mv1; int oi1 = mi1;
            mv1 = b1; mi1 = ib1;
            if (gt_pair(b2, ib2, o1, oi1)) { mv2 = b2; mi2 = ib2; }
            else                           { mv2 = o1; mi2 = oi1; }
        } else if (gt_pair(b1, ib1, mv2, mi2)) {
            mv2 = b1; mi2 = ib1;
        }
        float t  = expf(mv2 - mv1);     // <= 1
        float g1 = 1.f / (1.f + t);
        res[tid] = make_float4(g1, __int_as_float(mi1),
                               t * g1, __int_as_float(mi2));
    }
    __syncthreads();

    {   // write full 64x64 out tile: thread -> row tid>>3, 8-col segment
        int rr  = tid >> 3;          // 0..63
        int seg = tid & 7;           // 0..7
        float4 rv = res[rr];
        float g1 = rv.x, g2 = rv.z;
        int   j1 = __float_as_int(rv.y), j2 = __float_as_int(rv.w);
        float* op = out + (size_t)(row0 + rr) * NEXP + seg * 8;
        #pragma unroll
        for (int qq = 0; qq < 2; ++qq) {
            int e0 = seg * 8 + qq * 4;
            float4 o;
            o.x = (e0 + 0 == j1) ? g1 : ((e0 + 0 == j2) ? g2 : 0.f);
            o.y = (e0 + 1 == j1) ? g1 : ((e0 + 1 == j2) ? g2 : 0.f);
            o.z = (e0 + 2 == j1) ? g1 : ((e0 + 2 == j2) ? g2 : 0.f);
            o.w = (e0 + 3 == j1) ? g1 : ((e0 + 3 == j2) ? g2 : 0.f);
            *(float4*)(op + qq * 4) = o;
        }
    }
}

extern "C" void kernel_launch(void* const* d_in, const int* in_sizes, int n_in,
                              void* d_out, int out_size, void* d_ws, size_t ws_size,
                              hipStream_t stream) {
    const float* x     = (const float*)d_in[0];
    const float* wg    = (const float*)d_in[1];
    const float* wn    = (const float*)d_in[2];
    const float* noise = (const float*)d_in[3];
    float* out = (float*)d_out;
    _Float16* wsB = (_Float16*)d_ws;   // needs 64*2*8*1KB = 1 MB

    presplit_kernel<<<dim3(128), 256, 0, stream>>>(wg, wn, wsB);

    const int Brows = in_sizes[0] / DIMK;          // 32768
    dim3 grid(Brows / BM);                         // 512 blocks -> 2/CU, 16 waves/CU
    routing_mfma<<<grid, 512, 0, stream>>>(x, wsB, noise, out);
}

// Round 6
// 435.757 us; speedup vs baseline: 1.1137x; 1.1137x over previous
//
#include <hip/hip_runtime.h>
#include <math.h>

// RoutingLayer fused via split-fp16 MFMA emulation of fp32 GEMM.
// routing = x@w_gate + noise*(softplus(x@w_noise)+0.01); out = scatter(softmax(top2)).
// x: 32768x2048 fp32, w_*: 2048x64 fp32, noise: 32768x64, out: 32768x64.
//
// R9: 32x32x16 MFMA restructure. R8 proved the compiler sinks reg-staged B
// loads (VGPR=60 => pipeline collapsed, 223us); LDS-DMA staging is the only
// un-sinkable path. R7's pipe-sum (TA 41 + LDS 41 + VALU 30 + MFMA 25us)
// says every pipe's per-row cost must drop: with 32x32x16 frags a wave
// covers 32 rows x 64 cols per chunk -> ds_read/row halved, B-DMA/row
// halved, wave-steps/row halved, MFMA cycles -20%.
// Block: 256 thr = 4 waves (2 row-groups x 2 expert-halves), BM=64,
// grid 512 -> 2 independent blocks/CU (cross-block overlap at barriers).
// B: LDS quad-buffer [4][16KB], 2-deep prefetch, vmcnt(8) counted waits
// (8 VMEM/wave/step: 4 DMA + 4 x-float4). x: reg quad-buffer + convert
// one chunk ahead. VGPR budget 256 (2 waves/SIMD) -> pipeline state fits.

typedef _Float16 half8v __attribute__((ext_vector_type(8)));
typedef float f32x4  __attribute__((ext_vector_type(4)));
typedef float f32x16 __attribute__((ext_vector_type(16)));

constexpr int DIMK = 2048;
constexpr int NEXP = 64;
constexpr int BM   = 64;         // rows per block
constexpr int NCH  = DIMK / 32;  // 64 k-chunks of 32

__device__ __forceinline__ void async_load16(const void* g, void* l) {
    // global -> LDS DMA, 16B/lane; LDS dest = uniform base + lane*16
    __builtin_amdgcn_global_load_lds(
        (const __attribute__((address_space(1))) unsigned int*)g,
        (__attribute__((address_space(3))) unsigned int*)l, 16, 0, 0);
}

__device__ __forceinline__ bool gt_pair(float a, int ia, float b, int ib) {
    return (a > b) || (a == b && ia < ib);   // jax top_k: lower index wins ties
}

// ---- pre-kernel: split w' = 65536*[wg|wn] into 2 fp16 planes in 32x32x16
// B-frag order. Frag-block fb = c*16 + kh*8 + p*4 + nt  (1KB each, 1MB total):
// lane holds B[k = c*32 + kh*16 + (lane>>5)*8 + j][n' = nt*32 + (lane&31)]
// where nt 0,1 = w_gate cols 0..63 and nt 2,3 = w_noise cols 0..63.
__global__ __launch_bounds__(256)
void presplit_kernel(const float* __restrict__ wg, const float* __restrict__ wn,
                     _Float16* __restrict__ wsB)
{
    int gid  = blockIdx.x * 256 + threadIdx.x;   // 0..65535 = (fb, lane)
    int lane = gid & 63;
    int fb   = gid >> 6;          // 0..1023
    int nt   = fb & 3;
    int p    = (fb >> 2) & 1;
    int kh   = (fb >> 3) & 1;
    int c    = fb >> 4;
    const float* src = (nt < 2) ? (wg + nt * 32 + (lane & 31))
                                : (wn + (nt - 2) * 32 + (lane & 31));
    int kb = c * 32 + kh * 16 + ((lane >> 5) << 3);
    half8v hp;
    #pragma unroll
    for (int j = 0; j < 8; ++j) {
        float w = src[(size_t)(kb + j) * NEXP] * 65536.0f;
        _Float16 a = (_Float16)w;
        hp[j] = p ? (_Float16)(w - (float)a) : a;
    }
    *(half8v*)(wsB + (size_t)fb * 512 + lane * 8) = hp;
}

// ---- main kernel: 256 threads = 4 waves as (rg = row-group, colh = expert half).
// Wave tile: 32 rows x [32 gate cols | matching 32 noise cols] via 32x32x16.
__global__ __launch_bounds__(256, 2)
void routing_mfma(const float* __restrict__ x, const _Float16* __restrict__ wsB,
                  const float* __restrict__ noise, float* __restrict__ out)
{
    __shared__ _Float16 Bp[4][16][64][8];     // 64 KB: quad-buffered B frags
    __shared__ float4   cand[BM][2];          // 1 KB
    __shared__ float4   res[BM];              // 1 KB

    const int tid  = threadIdx.x;
    const int lane = tid & 63;
    const int w    = tid >> 6;          // 0..3
    const int rg   = w >> 1;            // row group (0,1): rows rg*32..rg*32+31
    const int colh = w & 1;             // expert half (0,1)
    const int m    = lane & 31;
    const int h    = lane >> 5;
    const int row0 = blockIdx.x * BM;

    f32x16 acc[2] = {};                 // [0]=gate tile, [1]=noise tile
    float4 ra[4][4];                    // raw x quad-buffer (slot idx literal)
    half8v afH[2][2], afL[2][2];        // converted-A dbuf [buf][kh]

    // A-frag source: lane holds A[row = rg*32+m][k = c*32 + kh*16 + h*8 + j]
    const float* xp = x + (size_t)(row0 + rg * 32 + m) * DIMK + h * 8;

    auto issue_B = [&](int c, int buf) {
        #pragma unroll
        for (int ii = 0; ii < 4; ++ii) {          // 16 x 1KB frag blocks / chunk
            int idx = w * 4 + ii;
            const _Float16* g = wsB + ((size_t)c * 16 + idx) * 512 + lane * 8;
            async_load16(g, &Bp[buf][idx][0][0]);
        }
    };

#define ISSUE_X(C, S)                                            \
    {   const float* p_ = xp + (C) * 32;                         \
        ra[S][0] = *(const float4*)(p_);                         \
        ra[S][1] = *(const float4*)(p_ + 4);                     \
        ra[S][2] = *(const float4*)(p_ + 16);                    \
        ra[S][3] = *(const float4*)(p_ + 20);  }

// convert ra[(C)&3] -> afH[P]/afL[P]  (P literal)
#define CONVERT(C, P)                                                        \
    {   _Pragma("unroll")                                                    \
        for (int kh = 0; kh < 2; ++kh) {                                     \
            float4 u = ra[(C) & 3][kh * 2];                                  \
            float4 v = ra[(C) & 3][kh * 2 + 1];                              \
            float f0 = u.x * 1024.f, f1 = u.y * 1024.f;                      \
            float f2 = u.z * 1024.f, f3 = u.w * 1024.f;                      \
            float f4 = v.x * 1024.f, f5 = v.y * 1024.f;                      \
            float f6 = v.z * 1024.f, f7 = v.w * 1024.f;                      \
            _Float16 a0=(_Float16)f0, a1=(_Float16)f1, a2=(_Float16)f2,      \
                     a3=(_Float16)f3, a4=(_Float16)f4, a5=(_Float16)f5,      \
                     a6=(_Float16)f6, a7=(_Float16)f7;                       \
            afH[P][kh][0]=a0; afH[P][kh][1]=a1; afH[P][kh][2]=a2;            \
            afH[P][kh][3]=a3; afH[P][kh][4]=a4; afH[P][kh][5]=a5;            \
            afH[P][kh][6]=a6; afH[P][kh][7]=a7;                             \
            afL[P][kh][0]=(_Float16)(f0-(float)a0);                         \
            afL[P][kh][1]=(_Float16)(f1-(float)a1);                         \
            afL[P][kh][2]=(_Float16)(f2-(float)a2);                         \
            afL[P][kh][3]=(_Float16)(f3-(float)a3);                         \
            afL[P][kh][4]=(_Float16)(f4-(float)a4);                         \
            afL[P][kh][5]=(_Float16)(f5-(float)a5);                         \
            afL[P][kh][6]=(_Float16)(f6-(float)a6);                         \
            afL[P][kh][7]=(_Float16)(f7-(float)a7);                         \
        }                                                                    \
    }

#define FENCE() asm volatile("" ::: "memory")

    // One chunk. 8 VMEM ops per thread per STEP (4 DMA + 4 x float4),
    // batch-contiguous => vmcnt(8) retires batch T while T+1 (and T+2's
    // just-issued ops) stay in flight across the barrier.
#define STEP(T, ISS, CV, WN)                                                 \
    {                                                                        \
        asm volatile("s_waitcnt vmcnt(" #WN ")" ::: "memory");               \
        asm volatile("s_barrier" ::: "memory");                              \
        if (ISS) { issue_B((T) + 2, ((T) + 2) & 3);                          \
                   ISSUE_X((T) + 2, ((T) + 2) & 3); }                        \
        half8v bf[2][2][2];                                                  \
        _Pragma("unroll")                                                    \
        for (int kh = 0; kh < 2; ++kh)                                       \
            _Pragma("unroll")                                                \
            for (int p = 0; p < 2; ++p)                                      \
                _Pragma("unroll")                                            \
                for (int tl = 0; tl < 2; ++tl)                               \
                    bf[kh][p][tl] = *(const half8v*)                         \
                        &Bp[(T) & 3][kh * 8 + p * 4 + tl * 2 + colh][lane][0];\
        __builtin_amdgcn_s_setprio(1);                                       \
        _Pragma("unroll")                                                    \
        for (int tl = 0; tl < 2; ++tl)                                       \
            _Pragma("unroll")                                                \
            for (int kh = 0; kh < 2; ++kh) {                                 \
                acc[tl] = __builtin_amdgcn_mfma_f32_32x32x16_f16(            \
                    afH[(T) & 1][kh], bf[kh][0][tl], acc[tl], 0, 0, 0);      \
                acc[tl] = __builtin_amdgcn_mfma_f32_32x32x16_f16(            \
                    afH[(T) & 1][kh], bf[kh][1][tl], acc[tl], 0, 0, 0);      \
                acc[tl] = __builtin_amdgcn_mfma_f32_32x32x16_f16(            \
                    afL[(T) & 1][kh], bf[kh][0][tl], acc[tl], 0, 0, 0);      \
            }                                                                \
        __builtin_amdgcn_s_setprio(0);                                       \
        if (CV) CONVERT((T) + 1, ((T) + 1) & 1);                             \
    }

    // Prologue: batches 0,1 (fence keeps batch issue-order), pre-convert 0.
    issue_B(0, 0);
    ISSUE_X(0, 0);
    FENCE();
    issue_B(1, 1);
    ISSUE_X(1, 1);
    CONVERT(0, 0);

    #pragma unroll 1
    for (int t = 0; t < NCH - 4; t += 4) {
        STEP(t + 0, 1, 1, 8)
        STEP(t + 1, 1, 1, 8)
        STEP(t + 2, 1, 1, 8)
        STEP(t + 3, 1, 1, 8)
    }
    STEP(NCH - 4, 1, 1, 8)    // t=60: issues batch 62
    STEP(NCH - 3, 1, 1, 8)    // t=61: issues batch 63
    STEP(NCH - 2, 0, 1, 8)    // t=62: batch 62 done (only 63 outstanding)
    STEP(NCH - 1, 0, 0, 0)    // t=63: drain

#undef STEP
#undef CONVERT
#undef ISSUE_X
#undef FENCE

    // ---- epilogue ----
    // 32x32 C/D layout: col = lane&31, row = (reg&3) + 8*(reg>>2) + 4*(lane>>5).
    // Unscale by 2^-26 (1024*65536).
    const float s = 0x1p-26f;
    {
        const int e = colh * 32 + m;              // expert this lane owns
        #pragma unroll
        for (int reg = 0; reg < 16; ++reg) {
            int r    = (reg & 3) + 8 * (reg >> 2) + 4 * h;   // 0..31
            int grow = row0 + rg * 32 + r;
            float nz   = noise[(size_t)grow * NEXP + e];
            float gate = acc[0][reg] * s;
            float nv   = acc[1][reg] * s;
            float sp   = fmaxf(nv, 0.f) + log1pf(expf(-fabsf(nv)));
            float vv   = gate + nz * (sp + 0.01f);
            float v1 = vv; int i1 = e;
            float v2 = -INFINITY; int i2 = 0x7fffffff;
            #pragma unroll
            for (int mm = 1; mm <= 16; mm <<= 1) {   // butterfly over 32-lane group
                float b1 = __shfl_xor(v1, mm); int ib1 = __shfl_xor(i1, mm);
                float b2 = __shfl_xor(v2, mm); int ib2 = __shfl_xor(i2, mm);
                if (gt_pair(b1, ib1, v1, i1)) {
                    float o1 = v1; int oi1 = i1;
                    v1 = b1; i1 = ib1;
                    if (gt_pair(b2, ib2, o1, oi1)) { v2 = b2; i2 = ib2; }
                    else                           { v2 = o1; i2 = oi1; }
                } else if (gt_pair(b1, ib1, v2, i2)) {
                    v2 = b1; i2 = ib1;
                }
            }
            if (m == 0)
                cand[rg * 32 + r][colh] = make_float4(v1, __int_as_float(i1),
                                                      v2, __int_as_float(i2));
        }
    }
    __syncthreads();

    if (tid < BM) {   // merge the two expert-half candidates, softmax
        float4 c0 = cand[tid][0], c1 = cand[tid][1];
        float mv1 = c0.x; int mi1 = __float_as_int(c0.y);
        float mv2 = c0.z; int mi2 = __float_as_int(c0.w);
        float b1 = c1.x;  int ib1 = __float_as_int(c1.y);
        float b2 = c1.z;  int ib2 = __float_as_int(c1.w);
        if (gt_pair(b1, ib1, mv1, mi1)) {
            float o1 = mv1; int oi1 = mi1;
            mv1 = b1; mi1 = ib1;
            if (gt_pair(b2, ib2, o1, oi1)) { mv2 = b2; mi2 = ib2; }
            else                           { mv2 = o1; mi2 = oi1; }
        } else if (gt_pair(b1, ib1, mv2, mi2)) {
            mv2 = b1; mi2 = ib1;
        }
        float t  = expf(mv2 - mv1);     // <= 1
        float g1 = 1.f / (1.f + t);
        res[tid] = make_float4(g1, __int_as_float(mi1),
                               t * g1, __int_as_float(mi2));
    }
    __syncthreads();

    {   // write full 64x64 out tile: thread -> row tid>>2, 16-col segment
        int rr  = tid >> 2;
        int seg = tid & 3;
        float4 rv = res[rr];
        float g1 = rv.x, g2 = rv.z;
        int   j1 = __float_as_int(rv.y), j2 = __float_as_int(rv.w);
        float* op = out + (size_t)(row0 + rr) * NEXP + seg * 16;
        #pragma unroll
        for (int qq = 0; qq < 4; ++qq) {
            int e0 = seg * 16 + qq * 4;
            float4 o;
            o.x = (e0 + 0 == j1) ? g1 : ((e0 + 0 == j2) ? g2 : 0.f);
            o.y = (e0 + 1 == j1) ? g1 : ((e0 + 1 == j2) ? g2 : 0.f);
            o.z = (e0 + 2 == j1) ? g1 : ((e0 + 2 == j2) ? g2 : 0.f);
            o.w = (e0 + 3 == j1) ? g1 : ((e0 + 3 == j2) ? g2 : 0.f);
            *(float4*)(op + qq * 4) = o;
        }
    }
}

extern "C" void kernel_launch(void* const* d_in, const int* in_sizes, int n_in,
                              void* d_out, int out_size, void* d_ws, size_t ws_size,
                              hipStream_t stream) {
    const float* x     = (const float*)d_in[0];
    const float* wg    = (const float*)d_in[1];
    const float* wn    = (const float*)d_in[2];
    const float* noise = (const float*)d_in[3];
    float* out = (float*)d_out;
    _Float16* wsB = (_Float16*)d_ws;   // needs 1024 * 1KB = 1 MB

    presplit_kernel<<<dim3(256), 256, 0, stream>>>(wg, wn, wsB);

    const int Brows = in_sizes[0] / DIMK;          // 32768
    dim3 grid(Brows / BM);                         // 512 blocks -> 2/CU
    routing_mfma<<<grid, 256, 0, stream>>>(x, wsB, noise, out);
}